// Round 6
// baseline (305.781 us; speedup 1.0000x reference)
//
#include <hip/hip_runtime.h>
#include <math.h>

#define ALPHA 0.001f
#define EPS 1e-12f
#define IN_DIM 8192
#define OUT_DIM 4096
#define COL4 (IN_DIM / 4)          // 2048 float4 per row
#define NSEG 512
#define SEG_ROWS 8                 // OUT_DIM / NSEG

typedef float f32x4 __attribute__((ext_vector_type(4)));

// ws layout (floats): y[4096] | ssq[pad 16] | P[NSEG*IN_DIM = 4M floats]
#define WS_Y   0
#define WS_SSQ (OUT_DIM)           // 4096
#define WS_P   (OUT_DIM + 16)      // 4112 (byte offset 16448, 16B-aligned)

// ---- Kernel A: fused matvec + per-segment column partials (reads W ONCE) --
// grid: NSEG blocks; block: 512 threads (8 waves). Block s owns rows 8s..8s+7.
__global__ __launch_bounds__(512, 4) void kA(const float* __restrict__ W,
                                             const float* __restrict__ x,
                                             float* __restrict__ y,
                                             float* __restrict__ P) {
    const int s = blockIdx.x;
    const int t = threadIdx.x;
    const int wv = t >> 6, ln = t & 63;
    __shared__ float red[2][8];

    const float4* W4 = (const float4*)W;
    const float4* X4 = (const float4*)x;

    float4 xr[4];
#pragma unroll
    for (int c = 0; c < 4; ++c) xr[c] = X4[c * 512 + t];

    float4 acc[4];
#pragma unroll
    for (int c = 0; c < 4; ++c) acc[c] = make_float4(0.f, 0.f, 0.f, 0.f);

    const int j0 = s * SEG_ROWS;
#pragma unroll
    for (int j = 0; j < SEG_ROWS; ++j) {
        float4 w[4];
#pragma unroll
        for (int c = 0; c < 4; ++c)
            w[c] = W4[(size_t)(j0 + j) * COL4 + c * 512 + t];
        float p = 0.f;
#pragma unroll
        for (int c = 0; c < 4; ++c)
            p += w[c].x * xr[c].x + w[c].y * xr[c].y +
                 w[c].z * xr[c].z + w[c].w * xr[c].w;
#pragma unroll
        for (int off = 32; off; off >>= 1) p += __shfl_xor(p, off, 64);
        if (ln == 0) red[j & 1][wv] = p;
        __syncthreads();
        float yj = 0.f;
#pragma unroll
        for (int k = 0; k < 8; ++k) yj += red[j & 1][k];
        if (t == 0) y[j0 + j] = yj;
#pragma unroll
        for (int c = 0; c < 4; ++c) {
            acc[c].x += w[c].x * yj;
            acc[c].y += w[c].y * yj;
            acc[c].z += w[c].z * yj;
            acc[c].w += w[c].w * yj;
        }
    }
    float4* P4 = (float4*)P;
#pragma unroll
    for (int c = 0; c < 4; ++c)
        P4[(size_t)s * COL4 + c * 512 + t] = acc[c];
}

// ---- Kernel B: exclusive scan of P over segments; block 0 reduces ssq -----
// grid: 32 blocks x 64 threads = 2048 threads (one float4-col each)
__global__ __launch_bounds__(64) void kB(float* __restrict__ P,
                                         const float* __restrict__ y,
                                         float* __restrict__ ssq) {
    if (blockIdx.x == 0) {
        // 64 threads reduce sum(y^2) over 4096
        float q = 0.f;
        for (int i = threadIdx.x; i < OUT_DIM; i += 64) {
            const float v = y[i];
            q += v * v;
        }
#pragma unroll
        for (int off = 32; off; off >>= 1) q += __shfl_xor(q, off, 64);
        if (threadIdx.x == 0) *ssq = q;
    }
    const int c4 = blockIdx.x * 64 + threadIdx.x;   // 0..2047
    float4* P4 = (float4*)P;
    float4 run = make_float4(0.f, 0.f, 0.f, 0.f);
#pragma unroll 8
    for (int s = 0; s < NSEG; ++s) {
        const float4 v = P4[(size_t)s * COL4 + c4];
        P4[(size_t)s * COL4 + c4] = run;
        run.x += v.x; run.y += v.y; run.z += v.z; run.w += v.w;
    }
}

// ---- Kernel C: local scan + Sanger update; writes yn and W_new ------------
// grid: (4, NSEG); block 512; col4 = bx*512 + t
__global__ __launch_bounds__(512, 4) void kC(const float* __restrict__ W,
                                             const float* __restrict__ x,
                                             const float* __restrict__ y,
                                             const float* __restrict__ P,
                                             const float* __restrict__ ssq,
                                             float* __restrict__ yn,
                                             float* __restrict__ Wout) {
    const int s = blockIdx.y;
    const int t = threadIdx.x;
    const int c4 = blockIdx.x * 512 + t;
    const float inv = 1.f / fmaxf(sqrtf(*ssq), EPS);
    const float a_s = ALPHA * inv;
    const float b_s = ALPHA * inv * inv;
    const int j0 = s * SEG_ROWS;

    if (blockIdx.x == 0 && t < SEG_ROWS) {
        yn[j0 + t] = y[j0 + t] * inv;
    }

    const float4* W4 = (const float4*)W;
    const float4* X4 = (const float4*)x;
    f32x4* O4 = (f32x4*)Wout;
    float4 run = ((const float4*)P)[(size_t)s * COL4 + c4];
    const float4 x4 = X4[c4];
#pragma unroll
    for (int j = 0; j < SEG_ROWS; ++j) {
        const float yj = y[j0 + j];
        const float aj = a_s * yj;
        const float bj = b_s * yj;
        const size_t idx = (size_t)(j0 + j) * COL4 + c4;
        const float4 w = W4[idx];
        run.x += w.x * yj; run.y += w.y * yj;
        run.z += w.z * yj; run.w += w.w * yj;
        f32x4 o;
        o.x = w.x + aj * x4.x - bj * run.x;
        o.y = w.y + aj * x4.y - bj * run.y;
        o.z = w.z + aj * x4.z - bj * run.z;
        o.w = w.w + aj * x4.w - bj * run.w;
        __builtin_nontemporal_store(o, &O4[idx]);
    }
}

extern "C" void kernel_launch(void* const* d_in, const int* in_sizes, int n_in,
                              void* d_out, int out_size, void* d_ws, size_t ws_size,
                              hipStream_t stream) {
    const float* x = (const float*)d_in[0];   // [8192]
    const float* W = (const float*)d_in[1];   // [4096, 8192]
    float* out = (float*)d_out;
    float* yn = out;                          // [4096]
    float* Wout = out + OUT_DIM;              // [4096*8192]

    float* ws = (float*)d_ws;
    float* y   = ws + WS_Y;
    float* ssq = ws + WS_SSQ;
    float* P   = ws + WS_P;

    // A: matvec + segment partials (single HBM pass over W)
    kA<<<dim3(NSEG), dim3(512), 0, stream>>>(W, x, y, P);
    // B: exclusive scan over segments + ssq reduce
    kB<<<dim3(32), dim3(64), 0, stream>>>(P, y, ssq);
    // C: local scan + update (nt stores; W read L3-resident)
    kC<<<dim3(4, NSEG), dim3(512), 0, stream>>>(W, x, y, P, ssq, yn, Wout);
}